// Round 16
// baseline (460.227 us; speedup 1.0000x reference)
//
#include <hip/hip_runtime.h>

// LSTM: B=2048, T=512, D=1, H=50, OUT=3, fp32.
//
// R17: antiphase dual-group pipeline. History (dispatch us):
//  R1-R4 582..539; R5 381; R6 291; R7 345; R8 268.6; R9 269 null;
//  R10 316; R11 FAIL; R12 214.5; R13 233; R14 230 (conflict removal
//  null); R15 228 (=R12, noise +-6%); R16 206.5 (single-term fp16 W_hh,
//  fp32 bias via MFMA C; absmax unchanged 4.88e-4 -> h-quant dominated).
// Model EXACT at R16: 512 x 968 cyc = 206.5us. Step = issue ~340 +
// ~600 exposed serial latency (barrier -> ds_read 120 -> MFMA -> trans
// update chain -> write -> barrier), phase-locked across 4 waves/SIMD.
//
// R17: one block = 32 batches as TWO groups (A=cols b0..b0+15,
// B=+16..+31) half a step out of phase. Per iteration, 2 barrier
// segments; in each, one group's ds_read+MFMA latency is covered by the
// OTHER group's register-resident update chain:
//   seg2(t):   readB(t) | updateA(t)->hA(t+1)+write+aug | MFMA_B | bar
//   seg1(t+1): readA(t+1) | updateB(t)->hB(t+1)+write+aug | MFMA_A | bar
// Buffer parity: h(t)/aug-x(t) land in buf t&1 one barrier before read.
// A-frags + bias_c shared by both groups (same weights). xs staging
// ELIMINATED: xwriter lanes (w15,hi3) read x from global with a 1-iter
// prefetch register (~700cyc cover). Grid 64 x 1024.
// All per-group math = R16 (verified): single-term fp16 W_hh, L-prescale,
// fp32 bias as MFMA C-operand, 2-term x (XSC=32), merged-rcp cell,
// fp16 h, guarded h-writes. Conventions (R5-R16): A row=lane&15
// (gate=R&3, unit=4w+(R>>2)), k=8*hi+e (+32/K-step); B col=lane&15,
// same k; D col=lane&15, row=4*hi+reg.

#define BB 2048
#define TT 512
#define HH 50
#define NB 16            // batches per GROUP (= MFMA cols); 2 groups/block
#define NW 16            // waves = tiles; 64 unit slots (50 real)
#define HS 72            // hf unit-slot stride per batch row (u16; 144B)
#define XSC   32.0f      // x-lo scale (keeps both fp16 factors normal)
#define XSCI  0.03125f   // 1/32
#define L1 -1.4426950408889634f      // -log2(e)
#define L2 -2.8853900817779268f      // -2*log2(e)

typedef __attribute__((ext_vector_type(4))) float          f32x4;
typedef __attribute__((ext_vector_type(8))) _Float16       f16x8;
typedef __attribute__((ext_vector_type(4))) unsigned short u16x4;

#define F16BITS(v) __builtin_bit_cast(unsigned short, (_Float16)(v))

__global__ __launch_bounds__(NW * 64)
void lstm_r17_kernel(const float* __restrict__ x,
                     const float* __restrict__ W_ih,
                     const float* __restrict__ W_hh,
                     const float* __restrict__ b_ih,
                     const float* __restrict__ b_hh,
                     const float* __restrict__ fc_w,
                     const float* __restrict__ fc_b,
                     float* __restrict__ out) {
    __shared__ __align__(16) unsigned short hfA[2][NB][HS];  // 4.6 KB
    __shared__ __align__(16) unsigned short hfB[2][NB][HS];  // 4.6 KB
    __shared__ float hfin[2][NB][64];                        // 8 KB (epilogue)

    const int tid  = threadIdx.x;
    const int w    = tid >> 6;          // wave id = tile id, 0..15
    const int lane = tid & 63;
    const int hi   = lane >> 4;
    const int bcol = lane & 15;         // batch column within group
    const int b0   = blockIdx.x * (2 * NB);

    // ---- zero h state (both groups, both buffers, incl. aug slots) ----
    for (int idx = tid; idx < (int)(sizeof(hfA) / 4); idx += NW * 64) {
        ((unsigned*)hfA)[idx] = 0;
        ((unsigned*)hfB)[idx] = 0;
    }

    // ---- A-fragments: permuted rows, L-prescaled single fp16 (R16) ----
    const int ga = bcol & 3;
    const int ua = 4 * w + (bcol >> 2);
    const bool ok = (ua < HH);
    const float Lg = (ga == 2) ? L2 : L1;
    f16x8 Ah0, Ah1;
    #pragma unroll
    for (int s = 0; s < 2; ++s) {
        #pragma unroll
        for (int e = 0; e < 8; ++e) {
            const int k = 32 * s + 8 * hi + e;
            _Float16 ah = (_Float16)0.0f;
            if (ok) {
                if (k < HH) {
                    ah = (_Float16)(Lg * W_hh[(ga * HH + ua) * HH + k]);   // RTN
                } else if (k == 61) {
                    ah = (_Float16)(Lg * W_ih[ga * HH + ua] * XSCI);
                } else if (k == 63) {
                    ah = (_Float16)(Lg * W_ih[ga * HH + ua]);
                }
            }
            if (s == 0) Ah0[e] = ah; else Ah1[e] = ah;
        }
    }

    // ---- bias as fp32 C-operand (exact; zero per-step VALU) ----
    f32x4 bias_c;
    #pragma unroll
    for (int r = 0; r < 4; ++r) {
        const int u = 4 * w + hi;
        const float Lr = (r == 2) ? L2 : L1;
        bias_c[r] = (u < HH) ? Lr * (b_ih[r * HH + u] + b_hh[r * HH + u]) : 0.0f;
    }

    // ---- LDS pointers (u16 units; buf stride = NB*HS = 1152) ----
    const unsigned short* rbA = &hfA[0][bcol][8 * hi];
    const unsigned short* rbB = &hfB[0][bcol][8 * hi];
    unsigned short* wbA  = &hfA[0][bcol][4 * w + hi];
    unsigned short* wbB  = &hfB[0][bcol][4 * w + hi];
    unsigned short* xwbA = &hfA[0][bcol][0];
    unsigned short* xwbB = &hfB[0][bcol][0];
    const bool xwriter = (w == 15) && (hi == 3);
    const bool hwriter = (4 * w + hi) < HH;   // pad units must not write

    // aug write: slots 60..63 = {0, x_lo*32, 0, x_hi} as one b64
#define AUGW(PTR, XV) { \
        const _Float16 xh_ = (_Float16)(XV); \
        const _Float16 xl_ = (_Float16)(((XV) - (float)xh_) * XSC); \
        u16x4 P_ = {0, __builtin_bit_cast(unsigned short, xl_), 0, \
                       __builtin_bit_cast(unsigned short, xh_)}; \
        *(u16x4*)((PTR) + 60) = P_; }

    float xAn = 0.0f, xBn = 0.0f;

    __syncthreads();   // zero-init complete

    // ---- prologue: aug x(0) -> buf0 (both groups); prefetch x(1) ----
    if (xwriter) {
        const float xa0 = x[(b0 + bcol) * TT + 0];
        const float xb0 = x[(b0 + NB + bcol) * TT + 0];
        AUGW(xwbA, xa0)
        AUGW(xwbB, xb0)
        xAn = x[(b0 + bcol) * TT + 1];
        xBn = x[(b0 + NB + bcol) * TT + 1];
    }

    float cA = 0.0f, cB = 0.0f, hA = 0.0f, hB = 0.0f;
    f32x4 accA, accB;

    __syncthreads();

    // merged-rcp LSTM cell (R9/R16-verified algebra); rows L-prescaled
#define UPDATE(ACC, CC, HO) { \
        const float E1 = __builtin_amdgcn_exp2f((ACC)[0]);   /* i */ \
        const float E2 = __builtin_amdgcn_exp2f((ACC)[1]);   /* f */ \
        const float G  = __builtin_amdgcn_exp2f((ACC)[2]);   /* g */ \
        const float E4 = __builtin_amdgcn_exp2f((ACC)[3]);   /* o */ \
        const float P1 = 1.0f + E1, P2 = 1.0f + E2; \
        const float PG = 1.0f + G,  P4 = 1.0f + E4; \
        const float MG = 1.0f - G; \
        const float N  = fmaf((CC) * P1, PG, MG * P2); \
        const float D  = (P1 * P2) * PG; \
        CC = N * __builtin_amdgcn_rcpf(D); \
        const float C5 = __builtin_amdgcn_exp2f(L2 * (CC)); \
        const float Q  = (1.0f + C5) * P4; \
        HO = (1.0f - C5) * __builtin_amdgcn_rcpf(Q); }

    // ---- peeled seg1(0): readA(0) -> MFMA_A -> accA(0) ----
    {
        const f16x8 B0_ = *(const f16x8*)(rbA);
        const f16x8 B1_ = *(const f16x8*)(rbA + 32);
        accA = __builtin_amdgcn_mfma_f32_16x16x32_f16(Ah0, B0_, bias_c, 0, 0, 0);
        accA = __builtin_amdgcn_mfma_f32_16x16x32_f16(Ah1, B1_, accA, 0, 0, 0);
        __syncthreads();
    }

    #pragma unroll 1
    for (int t = 0; t < TT; ++t) {
        const int cb  = t & 1;
        const int nb2 = 1 - cb;
        // ---- seg2(t): readB(t) | updateA(t) | MFMA_B(t) | barrier ----
        {
            const f16x8 B0_ = *(const f16x8*)(rbB + cb * 1152);
            const f16x8 B1_ = *(const f16x8*)(rbB + cb * 1152 + 32);
            UPDATE(accA, cA, hA)                       // hA(t+1)
            if (hwriter) wbA[nb2 * 1152] = F16BITS(hA);
            if (xwriter) {
                AUGW(xwbA + nb2 * 1152, xAn)           // aug xA(t+1)
                xAn = x[(b0 + bcol) * TT + ((t + 2 < TT) ? (t + 2) : (TT - 1))];
            }
            accB = __builtin_amdgcn_mfma_f32_16x16x32_f16(Ah0, B0_, bias_c, 0, 0, 0);
            accB = __builtin_amdgcn_mfma_f32_16x16x32_f16(Ah1, B1_, accB, 0, 0, 0);
            __syncthreads();
        }
        // ---- seg1(t+1): readA(t+1) | updateB(t) | MFMA_A(t+1) | barrier ----
        {
            const f16x8 B0_ = *(const f16x8*)(rbA + nb2 * 1152);
            const f16x8 B1_ = *(const f16x8*)(rbA + nb2 * 1152 + 32);
            UPDATE(accB, cB, hB)                       // hB(t+1)
            if (hwriter) wbB[nb2 * 1152] = F16BITS(hB);
            if (xwriter) {
                AUGW(xwbB + nb2 * 1152, xBn)           // aug xB(t+1)
                xBn = x[(b0 + NB + bcol) * TT + ((t + 2 < TT) ? (t + 2) : (TT - 1))];
            }
            accA = __builtin_amdgcn_mfma_f32_16x16x32_f16(Ah0, B0_, bias_c, 0, 0, 0);
            accA = __builtin_amdgcn_mfma_f32_16x16x32_f16(Ah1, B1_, accA, 0, 0, 0);
            __syncthreads();
        }
    }
#undef UPDATE
#undef AUGW
    // After t=511: seg2 gave hA(512); seg1 gave hB(512). (Final MFMA_A
    // and the t+1=512 aug/h writes are harmless: clamped x, unread bufs.)

    // ---- epilogue: h_T dot fc_w, both groups ----
    hfin[0][bcol][4 * w + hi] = hA;     // pad units hold exact 0
    hfin[1][bcol][4 * w + hi] = hB;
    __syncthreads();
    if (tid < 2 * NB * 3) {
        const int bl = tid / 3, o = tid % 3;     // bl 0..31
        const int g = bl >> 4, bc = bl & 15;
        float s = fc_b[o];
        for (int uu = 0; uu < HH; ++uu)
            s = fmaf(hfin[g][bc][uu], fc_w[o * HH + uu], s);
        out[(b0 + bl) * 3 + o] = s;
    }
}

extern "C" void kernel_launch(void* const* d_in, const int* in_sizes, int n_in,
                              void* d_out, int out_size, void* d_ws, size_t ws_size,
                              hipStream_t stream) {
    const float* x    = (const float*)d_in[0];
    const float* W_ih = (const float*)d_in[1];
    const float* W_hh = (const float*)d_in[2];
    const float* b_ih = (const float*)d_in[3];
    const float* b_hh = (const float*)d_in[4];
    const float* fc_w = (const float*)d_in[5];
    const float* fc_b = (const float*)d_in[6];
    float* out = (float*)d_out;

    dim3 grid(BB / (2 * NB));    // 64 blocks x 32 batches
    dim3 block(NW * 64);         // 1024 threads = 16 waves (4 per SIMD)
    lstm_r17_kernel<<<grid, block, 0, stream>>>(x, W_ih, W_hh, b_ih, b_hh,
                                                fc_w, fc_b, out);
}

// Round 17
// 261.724 us; speedup vs baseline: 1.7584x; 1.7584x over previous
//
#include <hip/hip_runtime.h>

// LSTM: B=2048, T=512, D=1, H=50, OUT=3, fp32.
//
// R18 = exact R16 resubmission (best verified: 206.5us dispatch, absmax
// 4.88e-4). History (dispatch us):
//  R1-R4 582..539 VALU-bound lane=unit; R5 381; R6 291; R7 345; R8 268.6;
//  R9 269 null; R10 316; R11 FAIL; R12 214.5; R13 233; R14 230 (conflict
//  removal null); R15 228 (=R12, noise +-6%); R16 206.5 (single-term fp16
//  W_hh, fp32 bias via MFMA C); R17 403 (antiphase dual-group: REFUTED --
//  each barrier segment costs ~950 cyc regardless of content; merging two
//  parallel blocks into two segments serialized them).
//
// FINAL MODEL (model-exact at R16: 512 x 968 cyc = 206.5us):
//  The recurrence needs 512 cross-wave h-exchanges; each barrier-segment
//  has a ~900-950 cyc fixed cost (16-wave barrier convergence + LDS
//  write->read turnaround + ds_read ~120 + MFMA + trans update chain).
//  No pipe exceeds 30% (VALU 26, Mfma 6.4, LDS conflicts null-tested) --
//  this is a latency floor, not a throughput roofline. Measured axes:
//  NW{4,8,13,16}->16; layout{strided,frag}->strided (conflicts not on
//  critical path); precision bf16-3term->fp16-2term->fp16-1term; K-aug
//  (bias/x into MFMA) -20%; merged-rcp null; masking null; antiphase
//  regression. 512 x ~950 = ~200us structural floor; R16 sits on it.
//
// Structure (R5-R16 verified conventions):
//  * NW=16 waves, 1 tile each; unit = 4w+hi; 4 waves/SIMD balanced.
//  * W_hh single-term fp16 RTN, L-prescaled (-log2e; -2log2e for g).
//  * bias as fp32 MFMA C-operand (exact, zero per-step VALU).
//  * x 2-term fp16 (XSC=32) in aug slots 61/63 of the already-read B1
//    frag; wave15 (all-pad) maintains them; h-writes guarded to u<50.
//  * fp16 h, double-buffered hf[2][NB][72]; ONE barrier per step;
//    merged-rcp cell. A row=lane&15 (gate=R&3, unit=4w+(R>>2)),
//    k=8*hi+e (+32/K-step); B col=lane&15 same k; D col=lane&15,
//    row=4*hi+reg.

#define BB 2048
#define TT 512
#define HH 50
#define NB 16            // batches per block (= MFMA cols)
#define NW 16            // waves = tiles; 64 unit slots (50 real)
#define XP 513           // xs row stride (floats)
#define HS 72            // hf unit-slot stride per batch row (u16; 144B)
#define XSC   32.0f      // x-lo scale (keeps both fp16 factors normal)
#define XSCI  0.03125f   // 1/32
#define L1 -1.4426950408889634f      // -log2(e)
#define L2 -2.8853900817779268f      // -2*log2(e)

typedef __attribute__((ext_vector_type(4))) float          f32x4;
typedef __attribute__((ext_vector_type(8))) _Float16       f16x8;
typedef __attribute__((ext_vector_type(4))) unsigned short u16x4;

__global__ __launch_bounds__(NW * 64)
void lstm_r18_kernel(const float* __restrict__ x,
                     const float* __restrict__ W_ih,
                     const float* __restrict__ W_hh,
                     const float* __restrict__ b_ih,
                     const float* __restrict__ b_hh,
                     const float* __restrict__ fc_w,
                     const float* __restrict__ fc_b,
                     float* __restrict__ out) {
    __shared__ float xs[NB * XP];                           // 32.8 KB
    __shared__ __align__(16) unsigned short hf[2][NB][HS];  // 4.6 KB (fp16 h + aug)
    __shared__ float hfin[NB][64];                          // 4 KB

    const int tid  = threadIdx.x;
    const int w    = tid >> 6;          // wave id = tile id, 0..15
    const int lane = tid & 63;
    const int hi   = lane >> 4;
    const int bcol = lane & 15;         // batch column
    const int b0   = blockIdx.x * NB;

    // ---- stage x rows (coalesced) + zero pad col 512 ----
    for (int idx = tid; idx < NB * TT; idx += NW * 64) {
        xs[(idx >> 9) * XP + (idx & 511)] = x[(b0 + (idx >> 9)) * TT + (idx & 511)];
    }
    if (tid < NB) xs[tid * XP + 512] = 0.0f;
    // ---- zero h state (both buffers incl. all pad/aug slots) ----
    for (int idx = tid; idx < (int)(sizeof(hf) / 4); idx += NW * 64) {
        ((unsigned*)hf)[idx] = 0;
    }

    // ---- A-fragments: permuted rows, L-prescaled single fp16 ----
    // Lane supplies A row R = lane&15: gate ga = R&3, unit ua = 4w+(R>>2).
    // k cols: [0,50) = fp16(Lg*W_hh); 61: fp16(Lg*W_ih/32) (pairs x_lo*32);
    // 63: fp16(Lg*W_ih) (pairs x_hi); rest 0. Bias moves to MFMA C.
    const int ga = bcol & 3;
    const int ua = 4 * w + (bcol >> 2);
    const bool ok = (ua < HH);
    const float Lg = (ga == 2) ? L2 : L1;
    f16x8 Ah0, Ah1;
    #pragma unroll
    for (int s = 0; s < 2; ++s) {
        #pragma unroll
        for (int e = 0; e < 8; ++e) {
            const int k = 32 * s + 8 * hi + e;
            _Float16 ah = (_Float16)0.0f;
            if (ok) {
                if (k < HH) {
                    ah = (_Float16)(Lg * W_hh[(ga * HH + ua) * HH + k]);   // RTN
                } else if (k == 61) {
                    ah = (_Float16)(Lg * W_ih[ga * HH + ua] * XSCI);
                } else if (k == 63) {
                    ah = (_Float16)(Lg * W_ih[ga * HH + ua]);
                }
            }
            if (s == 0) Ah0[e] = ah; else Ah1[e] = ah;
        }
    }

    // ---- bias as fp32 C-operand: reg r <-> gate r of unit 4w+hi ----
    f32x4 bias_c;
    #pragma unroll
    for (int r = 0; r < 4; ++r) {
        const int u = 4 * w + hi;
        const float Lr = (r == 2) ? L2 : L1;
        bias_c[r] = (u < HH) ? Lr * (b_ih[r * HH + u] + b_hh[r * HH + u]) : 0.0f;
    }

    // ---- LDS pointers (u16 units). buf stride = NB*HS = 1152 ----
    const unsigned short* rb  = &hf[0][bcol][8 * hi];    // B-frag reads
    unsigned short*       wb  = &hf[0][bcol][4 * w + hi];// h write (unit slot)
    unsigned short*       xwb = &hf[0][bcol][0];         // aug writes
    const bool xwriter = (w == 15) && (hi == 3);
    const bool hwriter = (4 * w + hi) < HH;   // pad units must not write

    __syncthreads();   // zero-init complete

    // ---- prologue aug write: x(0) -> buf0 slots 60..63 = {0,xl,0,xh} ----
    if (xwriter) {
        const float x0 = xs[bcol * XP + 0];
        const _Float16 xh = (_Float16)x0;
        const _Float16 xl = (_Float16)((x0 - (float)xh) * XSC);
        u16x4 P = {0, __builtin_bit_cast(unsigned short, xl), 0,
                      __builtin_bit_cast(unsigned short, xh)};
        *(u16x4*)(xwb + 60) = P;
    }

    float c = 0.0f, hcur = 0.0f;

    __syncthreads();

    // One step: read buf CB (h(t-1) + aug x(t)), write buf 1-CB, one barrier.
#define STEP(CB, T) { \
        const f16x8 B0 = *(const f16x8*)(rb + (CB) * 1152); \
        const f16x8 B1 = *(const f16x8*)(rb + (CB) * 1152 + 32); \
        f32x4 acc = __builtin_amdgcn_mfma_f32_16x16x32_f16(Ah0, B0, bias_c, 0, 0, 0); \
        acc = __builtin_amdgcn_mfma_f32_16x16x32_f16(Ah1, B1, acc, 0, 0, 0); \
        const float E1 = __builtin_amdgcn_exp2f(acc[0]);   /* i */ \
        const float E2 = __builtin_amdgcn_exp2f(acc[1]);   /* f */ \
        const float G  = __builtin_amdgcn_exp2f(acc[2]);   /* g */ \
        const float E4 = __builtin_amdgcn_exp2f(acc[3]);   /* o */ \
        const float P1 = 1.0f + E1, P2 = 1.0f + E2; \
        const float PG = 1.0f + G,  P4 = 1.0f + E4; \
        const float MG = 1.0f - G; \
        const float N  = fmaf(c * P1, PG, MG * P2); \
        const float D  = (P1 * P2) * PG; \
        c = N * __builtin_amdgcn_rcpf(D); \
        const float C5 = __builtin_amdgcn_exp2f(L2 * c); \
        const float Q  = (1.0f + C5) * P4; \
        hcur = (1.0f - C5) * __builtin_amdgcn_rcpf(Q); \
        if (hwriter) \
            wb[(1 - (CB)) * 1152] = __builtin_bit_cast(unsigned short, (_Float16)hcur); \
        if (xwriter) { \
            const float xn = xs[bcol * XP + (T) + 1]; \
            const _Float16 xh = (_Float16)xn; \
            const _Float16 xl = (_Float16)((xn - (float)xh) * XSC); \
            u16x4 P = {0, __builtin_bit_cast(unsigned short, xl), 0, \
                          __builtin_bit_cast(unsigned short, xh)}; \
            *(u16x4*)(xwb + (1 - (CB)) * 1152 + 60) = P; \
        } \
        __syncthreads(); }

    #pragma unroll 1
    for (int t = 0; t < TT; t += 2) {
        STEP(0, t)
        STEP(1, t + 1)
    }
#undef STEP

    // ---- epilogue: h_T dot fc_w (once) ----
    hfin[bcol][4 * w + hi] = hcur;      // pad units hold exact 0
    __syncthreads();
    if (tid < NB * 3) {
        const int b = tid / 3, o = tid % 3;
        float s = fc_b[o];
        for (int uu = 0; uu < HH; ++uu)
            s = fmaf(hfin[b][uu], fc_w[o * HH + uu], s);
        out[(b0 + b) * 3 + o] = s;
    }
}

extern "C" void kernel_launch(void* const* d_in, const int* in_sizes, int n_in,
                              void* d_out, int out_size, void* d_ws, size_t ws_size,
                              hipStream_t stream) {
    const float* x    = (const float*)d_in[0];
    const float* W_ih = (const float*)d_in[1];
    const float* W_hh = (const float*)d_in[2];
    const float* b_ih = (const float*)d_in[3];
    const float* b_hh = (const float*)d_in[4];
    const float* fc_w = (const float*)d_in[5];
    const float* fc_b = (const float*)d_in[6];
    float* out = (float*)d_out;

    dim3 grid(BB / NB);      // 128 blocks
    dim3 block(NW * 64);     // 1024 threads = 16 waves (4 per SIMD)
    lstm_r18_kernel<<<grid, block, 0, stream>>>(x, W_ih, W_hh, b_ih, b_hh,
                                                fc_w, fc_b, out);
}